// Round 1
// baseline (227.004 us; speedup 1.0000x reference)
//
#include <hip/hip_runtime.h>

// LocalWindowAttn: B=32, H=W=56, D=256, WS=7, NHEAD=8, hd=32
// tokens = 100352, windows = 2048, qkv stored fp16 in d_ws (154 MB)

using f16   = _Float16;
using f16x4 = __attribute__((ext_vector_type(4))) _Float16;
using f16x8 = __attribute__((ext_vector_type(8))) _Float16;
using f32x4 = __attribute__((ext_vector_type(4))) float;

#define NTOK   100352
#define DMODEL 256
#define QKVN   768
#define LDSK   72   // 64 + 8 halves pad

__device__ __forceinline__ f16x8 zero8() {
    f16x8 z; 
#pragma unroll
    for (int i = 0; i < 8; ++i) z[i] = (f16)0;
    return z;
}

// ---------------- Kernel 1: qkv = (x @ in_w^T + b), q pre-scaled ----------------
__global__ __launch_bounds__(256) void qkv_gemm(
    const float* __restrict__ X,    // [100352,256]
    const float* __restrict__ W,    // [768,256]
    const float* __restrict__ bias, // [768]
    f16* __restrict__ QKV)          // [100352,768]
{
    __shared__ f16 As[128][LDSK];
    __shared__ f16 Bs[128][LDSK];
    const int tid  = threadIdx.x;
    const int lane = tid & 63;
    const int wave = tid >> 6;
    const int m0 = blockIdx.x * 128;
    const int n0 = blockIdx.y * 128;
    const int wm = (wave >> 1) * 64;
    const int wn = (wave & 1) * 64;
    const int g  = lane >> 4;
    const int lr = lane & 15;

    f32x4 acc[4][4] = {};

    for (int k0 = 0; k0 < 256; k0 += 64) {
#pragma unroll
        for (int j = 0; j < 8; ++j) {
            int v = tid + j * 256;           // 0..2047 float4 slots
            int row = v >> 4, cv = v & 15;
            float4 f = *reinterpret_cast<const float4*>(X + (size_t)(m0 + row) * 256 + k0 + cv * 4);
            f16x4 h; h[0]=(f16)f.x; h[1]=(f16)f.y; h[2]=(f16)f.z; h[3]=(f16)f.w;
            *reinterpret_cast<f16x4*>(&As[row][cv * 4]) = h;
        }
#pragma unroll
        for (int j = 0; j < 8; ++j) {
            int v = tid + j * 256;
            int row = v >> 4, cv = v & 15;
            float4 f = *reinterpret_cast<const float4*>(W + (size_t)(n0 + row) * 256 + k0 + cv * 4);
            f16x4 h; h[0]=(f16)f.x; h[1]=(f16)f.y; h[2]=(f16)f.z; h[3]=(f16)f.w;
            *reinterpret_cast<f16x4*>(&Bs[row][cv * 4]) = h;
        }
        __syncthreads();
#pragma unroll
        for (int ks = 0; ks < 2; ++ks) {
            f16x8 a[4], b[4];
#pragma unroll
            for (int i = 0; i < 4; ++i)
                a[i] = *reinterpret_cast<const f16x8*>(&As[wm + i * 16 + lr][ks * 32 + g * 8]);
#pragma unroll
            for (int i = 0; i < 4; ++i)
                b[i] = *reinterpret_cast<const f16x8*>(&Bs[wn + i * 16 + lr][ks * 32 + g * 8]);
#pragma unroll
            for (int mi = 0; mi < 4; ++mi)
#pragma unroll
                for (int ni = 0; ni < 4; ++ni)
                    acc[mi][ni] = __builtin_amdgcn_mfma_f32_16x16x32_f16(a[mi], b[ni], acc[mi][ni], 0, 0, 0);
        }
        __syncthreads();
    }
    const float scale = 0.17677669529663687f;  // 1/sqrt(32)
#pragma unroll
    for (int ni = 0; ni < 4; ++ni) {
        int n = n0 + wn + ni * 16 + lr;
        float bv = bias[n];
        float sc = (n < 256) ? scale : 1.0f;
#pragma unroll
        for (int mi = 0; mi < 4; ++mi)
#pragma unroll
            for (int r = 0; r < 4; ++r) {
                int m = m0 + wm + mi * 16 + g * 4 + r;
                QKV[(size_t)m * QKVN + n] = (f16)((acc[mi][ni][r] + bv) * sc);
            }
    }
}

// ---------------- Kernel 2: per-(window, head) attention ----------------
__global__ __launch_bounds__(64) void win_attn(f16* __restrict__ QKV)
{
    __shared__ f16 Vt[32][LDSK];   // [d][k]
    __shared__ f16 P[64][LDSK];    // [row][col]
    const int lane = threadIdx.x;
    const int widx = blockIdx.x;
    const int win = widx >> 3, h = widx & 7;
    const int b = win >> 6, wh = (win >> 3) & 7, ww = win & 7;
    const int base = (b * 56 + wh * 7) * 56 + ww * 7;
    const int g = lane >> 4, lr = lane & 15;

    auto tok = [&](int row) { int rr = row / 7; return base + rr * 56 + (row - rr * 7); };

    // q,k fragments straight from global
    f16x8 qf[4], kf[4];
#pragma unroll
    for (int i = 0; i < 4; ++i) {
        int row = i * 16 + lr;
        if (row < 49) {
            size_t off = (size_t)tok(row) * QKVN + h * 32 + g * 8;
            qf[i] = *reinterpret_cast<const f16x8*>(QKV + off);
            kf[i] = *reinterpret_cast<const f16x8*>(QKV + off + 256);
        } else { qf[i] = zero8(); kf[i] = zero8(); }
    }
    // stage V transposed
    {
        int kk = lane;
        if (kk < 49) {
            size_t off = (size_t)tok(kk) * QKVN + 512 + h * 32;
            f16x8 vv[4];
#pragma unroll
            for (int j = 0; j < 4; ++j)
                vv[j] = *reinterpret_cast<const f16x8*>(QKV + off + j * 8);
#pragma unroll
            for (int j = 0; j < 4; ++j)
#pragma unroll
                for (int d = 0; d < 8; ++d) Vt[j * 8 + d][kk] = vv[j][d];
        } else {
#pragma unroll
            for (int d = 0; d < 32; ++d) Vt[d][kk] = (f16)0;
        }
    }
    // scores (K=32, one MFMA per 16x16 tile)
    f32x4 s[4][4] = {};
#pragma unroll
    for (int mi = 0; mi < 4; ++mi)
#pragma unroll
        for (int ni = 0; ni < 4; ++ni)
            s[mi][ni] = __builtin_amdgcn_mfma_f32_16x16x32_f16(qf[mi], kf[ni], s[mi][ni], 0, 0, 0);

    // softmax (fp32) + P to LDS
    __syncthreads();
#pragma unroll
    for (int mi = 0; mi < 4; ++mi) {
#pragma unroll
        for (int r = 0; r < 4; ++r) {
            float vals[4];
            float mx = -1e30f;
#pragma unroll
            for (int ni = 0; ni < 4; ++ni) {
                int col = ni * 16 + lr;
                vals[ni] = s[mi][ni][r];
                if (col < 49) mx = fmaxf(mx, vals[ni]);
            }
#pragma unroll
            for (int d = 8; d >= 1; d >>= 1) mx = fmaxf(mx, __shfl_xor(mx, d, 64));
            float p[4], sum = 0.f;
#pragma unroll
            for (int ni = 0; ni < 4; ++ni) {
                int col = ni * 16 + lr;
                p[ni] = (col < 49) ? __expf(vals[ni] - mx) : 0.f;
                sum += p[ni];
            }
#pragma unroll
            for (int d = 8; d >= 1; d >>= 1) sum += __shfl_xor(sum, d, 64);
            float is = 1.f / sum;
            int row = mi * 16 + g * 4 + r;
#pragma unroll
            for (int ni = 0; ni < 4; ++ni)
                P[row][ni * 16 + lr] = (f16)(p[ni] * is);
        }
    }
    __syncthreads();

    // PV: [64,64] @ [64(k),32(d)]
    f32x4 o[4][2] = {};
#pragma unroll
    for (int ks = 0; ks < 2; ++ks) {
        f16x8 pa[4], vb[2];
#pragma unroll
        for (int mi = 0; mi < 4; ++mi)
            pa[mi] = *reinterpret_cast<const f16x8*>(&P[mi * 16 + lr][ks * 32 + g * 8]);
#pragma unroll
        for (int ni = 0; ni < 2; ++ni)
            vb[ni] = *reinterpret_cast<const f16x8*>(&Vt[ni * 16 + lr][ks * 32 + g * 8]);
#pragma unroll
        for (int mi = 0; mi < 4; ++mi)
#pragma unroll
            for (int ni = 0; ni < 2; ++ni)
                o[mi][ni] = __builtin_amdgcn_mfma_f32_16x16x32_f16(pa[mi], vb[ni], o[mi][ni], 0, 0, 0);
    }
    // write o over the q slot (same head's 32 halves -> no inter-block hazard)
#pragma unroll
    for (int mi = 0; mi < 4; ++mi)
#pragma unroll
        for (int r = 0; r < 4; ++r) {
            int row = mi * 16 + g * 4 + r;
            if (row < 49) {
                size_t off = (size_t)tok(row) * QKVN + h * 32;
#pragma unroll
                for (int ni = 0; ni < 2; ++ni)
                    QKV[off + ni * 16 + lr] = (f16)o[mi][ni][r];
            }
        }
}

// ---------------- Kernel 3: out = o @ out_w^T + out_b ----------------
__global__ __launch_bounds__(256) void out_gemm(
    const f16* __restrict__ O,      // rows stride 768, first 256 halves = o
    const float* __restrict__ W,    // [256,256]
    const float* __restrict__ bias, // [256]
    float* __restrict__ OUT)        // [100352,256]
{
    __shared__ f16 As[128][LDSK];
    __shared__ f16 Bs[128][LDSK];
    const int tid  = threadIdx.x;
    const int lane = tid & 63;
    const int wave = tid >> 6;
    const int m0 = blockIdx.x * 128;
    const int n0 = blockIdx.y * 128;
    const int wm = (wave >> 1) * 64;
    const int wn = (wave & 1) * 64;
    const int g  = lane >> 4;
    const int lr = lane & 15;

    f32x4 acc[4][4] = {};

    for (int k0 = 0; k0 < 256; k0 += 64) {
        // A tile: fp16 rows (stride 768)
#pragma unroll
        for (int j = 0; j < 4; ++j) {
            int v = tid + j * 256;           // 0..1023 f16x8 slots
            int row = v >> 3, cv = v & 7;
            f16x8 h = *reinterpret_cast<const f16x8*>(O + (size_t)(m0 + row) * QKVN + k0 + cv * 8);
            *reinterpret_cast<f16x8*>(&As[row][cv * 8]) = h;
        }
        // B tile: fp32 -> fp16
#pragma unroll
        for (int j = 0; j < 8; ++j) {
            int v = tid + j * 256;
            int row = v >> 4, cv = v & 15;
            float4 f = *reinterpret_cast<const float4*>(W + (size_t)(n0 + row) * 256 + k0 + cv * 4);
            f16x4 h; h[0]=(f16)f.x; h[1]=(f16)f.y; h[2]=(f16)f.z; h[3]=(f16)f.w;
            *reinterpret_cast<f16x4*>(&Bs[row][cv * 4]) = h;
        }
        __syncthreads();
#pragma unroll
        for (int ks = 0; ks < 2; ++ks) {
            f16x8 a[4], b[4];
#pragma unroll
            for (int i = 0; i < 4; ++i)
                a[i] = *reinterpret_cast<const f16x8*>(&As[wm + i * 16 + lr][ks * 32 + g * 8]);
#pragma unroll
            for (int i = 0; i < 4; ++i)
                b[i] = *reinterpret_cast<const f16x8*>(&Bs[wn + i * 16 + lr][ks * 32 + g * 8]);
#pragma unroll
            for (int mi = 0; mi < 4; ++mi)
#pragma unroll
                for (int ni = 0; ni < 4; ++ni)
                    acc[mi][ni] = __builtin_amdgcn_mfma_f32_16x16x32_f16(a[mi], b[ni], acc[mi][ni], 0, 0, 0);
        }
        __syncthreads();
    }
#pragma unroll
    for (int ni = 0; ni < 4; ++ni) {
        int n = n0 + wn + ni * 16 + lr;
        float bv = bias[n];
#pragma unroll
        for (int mi = 0; mi < 4; ++mi)
#pragma unroll
            for (int r = 0; r < 4; ++r) {
                int m = m0 + wm + mi * 16 + g * 4 + r;
                OUT[(size_t)m * 256 + n] = acc[mi][ni][r] + bv;
            }
    }
}

extern "C" void kernel_launch(void* const* d_in, const int* in_sizes, int n_in,
                              void* d_out, int out_size, void* d_ws, size_t ws_size,
                              hipStream_t stream) {
    const float* x     = (const float*)d_in[0];
    const float* in_w  = (const float*)d_in[1];
    const float* in_b  = (const float*)d_in[2];
    const float* out_w = (const float*)d_in[3];
    const float* out_b = (const float*)d_in[4];
    float* out = (float*)d_out;
    f16* qkv = (f16*)d_ws;   // needs 100352*768*2 = 154,140,672 B

    dim3 g1(NTOK / 128, QKVN / 128);
    qkv_gemm<<<g1, 256, 0, stream>>>(x, in_w, in_b, qkv);

    win_attn<<<2048 * 8, 64, 0, stream>>>(qkv);

    dim3 g3(NTOK / 128, DMODEL / 128);
    out_gemm<<<g3, 256, 0, stream>>>(qkv, out_w, out_b, out);
}

// Round 2
// 178.626 us; speedup vs baseline: 1.2708x; 1.2708x over previous
//
#include <hip/hip_runtime.h>

// LocalWindowAttn: B=32, H=W=56, D=256, WS=7, NHEAD=8, hd=32
// tokens = 100352, windows = 2048
// ws: qkv fp16 [100352,768] = 154,140,672 B
// d_out scratch (before final write): Xh fp16 [100352,256] + Wqh fp16 [768,256]

using f16   = _Float16;
using f16x4 = __attribute__((ext_vector_type(4))) _Float16;
using f16x8 = __attribute__((ext_vector_type(8))) _Float16;
using f32x4 = __attribute__((ext_vector_type(4))) float;

#define NTOK   100352
#define DMODEL 256
#define QKVN   768
#define LDSK   72   // padded stride for cvt-staged tiles

typedef const __attribute__((address_space(1))) unsigned int* as1_u32p;
typedef __attribute__((address_space(3))) unsigned int* as3_u32p;

__device__ __forceinline__ void gload16(const void* g, void* l) {
    __builtin_amdgcn_global_load_lds((as1_u32p)g, (as3_u32p)l, 16, 0, 0);
}

__device__ __forceinline__ f16x8 zero8() {
    f16x8 z;
#pragma unroll
    for (int i = 0; i < 8; ++i) z[i] = (f16)0;
    return z;
}

// ---------------- Kernel 0: fp32 -> fp16 convert (X, in_proj_w with q-scale) ----------------
#define XV4   6422528   // 100352*256/4
#define WQV4  49152     // 768*256/4
__global__ __launch_bounds__(256) void convert_all(
    const float* __restrict__ X, const float* __restrict__ Wq,
    f16* __restrict__ Xh, f16* __restrict__ Wqh)
{
    const float scale = 0.17677669529663687f;  // 1/sqrt(32)
    const int total = XV4 + WQV4;
    for (int i = blockIdx.x * blockDim.x + threadIdx.x; i < total;
         i += gridDim.x * blockDim.x) {
        float4 f;
        f16x4 h;
        if (i < XV4) {
            f = reinterpret_cast<const float4*>(X)[i];
            h[0]=(f16)f.x; h[1]=(f16)f.y; h[2]=(f16)f.z; h[3]=(f16)f.w;
            reinterpret_cast<f16x4*>(Xh)[i] = h;
        } else {
            int idx = i - XV4;
            int row = idx >> 6;          // 64 vec4 per 256-col row
            float sc = (row < 256) ? scale : 1.0f;
            f = reinterpret_cast<const float4*>(Wq)[idx];
            h[0]=(f16)(f.x*sc); h[1]=(f16)(f.y*sc); h[2]=(f16)(f.z*sc); h[3]=(f16)(f.w*sc);
            reinterpret_cast<f16x4*>(Wqh)[idx] = h;
        }
    }
}

// ---------------- Kernel 1: qkv = Xh @ Wqh^T + b (q pre-scaled via Wqh) ----------------
// m97 structure: global_load_lds width-16, linear LDS [128][64] with
// rule-21 both-sides swizzle: 16B-slot cs ^= (row&7) on source AND read.
__global__ __launch_bounds__(256) void qkv_gemm(
    const f16* __restrict__ Xh,   // [100352,256]
    const f16* __restrict__ Wh,   // [768,256]
    const float* __restrict__ bias,
    f16* __restrict__ QKV)        // [100352,768]
{
    __shared__ f16 As[128 * 64];
    __shared__ f16 Bs[128 * 64];
    const int tid  = threadIdx.x;
    const int lane = tid & 63;
    const int wave = tid >> 6;
    // 1D grid, bijective XCD swizzle (nwg = 4704, %8 == 0), n fastest
    int wg = blockIdx.x;
    const int cpx = (NTOK / 128) * (QKVN / 128) / 8;
    wg = (wg & 7) * cpx + (wg >> 3);
    const int m0 = (wg / (QKVN / 128)) * 128;
    const int n0 = (wg % (QKVN / 128)) * 128;
    const int wm = (wave >> 1) * 64;
    const int wn = (wave & 1) * 64;
    const int g  = lane >> 4;
    const int lr = lane & 15;

    f32x4 acc[4][4] = {};

    for (int k0 = 0; k0 < 256; k0 += 64) {
#pragma unroll
        for (int j = 0; j < 4; ++j) {
            int s   = wave * 64 + lane + j * 256;   // 16B slot 0..1023
            int row = s >> 3;
            int cs  = (s & 7) ^ (row & 7);          // pre-swizzled source
            gload16(Xh + (size_t)(m0 + row) * 256 + k0 + cs * 8,
                    &As[(size_t)(wave * 64 + j * 256) * 8]);
            gload16(Wh + (size_t)(n0 + row) * 256 + k0 + cs * 8,
                    &Bs[(size_t)(wave * 64 + j * 256) * 8]);
        }
        __syncthreads();
#pragma unroll
        for (int ks = 0; ks < 2; ++ks) {
            f16x8 a[4], b[4];
#pragma unroll
            for (int i = 0; i < 4; ++i) {
                int row = wm + i * 16 + lr;
                int c   = ((ks << 2) + g) ^ (row & 7);  // swizzled read
                a[i] = *reinterpret_cast<const f16x8*>(&As[row * 64 + c * 8]);
            }
#pragma unroll
            for (int i = 0; i < 4; ++i) {
                int row = wn + i * 16 + lr;
                int c   = ((ks << 2) + g) ^ (row & 7);
                b[i] = *reinterpret_cast<const f16x8*>(&Bs[row * 64 + c * 8]);
            }
#pragma unroll
            for (int mi = 0; mi < 4; ++mi)
#pragma unroll
                for (int ni = 0; ni < 4; ++ni)
                    acc[mi][ni] = __builtin_amdgcn_mfma_f32_16x16x32_f16(a[mi], b[ni], acc[mi][ni], 0, 0, 0);
        }
        __syncthreads();
    }
    const float scale = 0.17677669529663687f;
#pragma unroll
    for (int ni = 0; ni < 4; ++ni) {
        int n = n0 + wn + ni * 16 + lr;
        float bv = bias[n];
        if (n < 256) bv *= scale;
#pragma unroll
        for (int mi = 0; mi < 4; ++mi)
#pragma unroll
            for (int r = 0; r < 4; ++r) {
                int m = m0 + wm + mi * 16 + g * 4 + r;
                QKV[(size_t)m * QKVN + n] = (f16)(acc[mi][ni][r] + bv);
            }
    }
}

// ---------------- Kernel 2: per-(window, head) attention ----------------
__global__ __launch_bounds__(64) void win_attn(f16* __restrict__ QKV)
{
    __shared__ f16 Vt[32][LDSK];   // [d][k]
    __shared__ f16 P[64][LDSK];    // [row][col]
    const int lane = threadIdx.x;
    const int widx = blockIdx.x;
    const int win = widx >> 3, h = widx & 7;
    const int b = win >> 6, wh = (win >> 3) & 7, ww = win & 7;
    const int base = (b * 56 + wh * 7) * 56 + ww * 7;
    const int g = lane >> 4, lr = lane & 15;

    auto tok = [&](int row) { int rr = row / 7; return base + rr * 56 + (row - rr * 7); };

    f16x8 qf[4], kf[4];
#pragma unroll
    for (int i = 0; i < 4; ++i) {
        int row = i * 16 + lr;
        if (row < 49) {
            size_t off = (size_t)tok(row) * QKVN + h * 32 + g * 8;
            qf[i] = *reinterpret_cast<const f16x8*>(QKV + off);
            kf[i] = *reinterpret_cast<const f16x8*>(QKV + off + 256);
        } else { qf[i] = zero8(); kf[i] = zero8(); }
    }
    {
        int kk = lane;
        if (kk < 49) {
            size_t off = (size_t)tok(kk) * QKVN + 512 + h * 32;
            f16x8 vv[4];
#pragma unroll
            for (int j = 0; j < 4; ++j)
                vv[j] = *reinterpret_cast<const f16x8*>(QKV + off + j * 8);
#pragma unroll
            for (int j = 0; j < 4; ++j)
#pragma unroll
                for (int d = 0; d < 8; ++d) Vt[j * 8 + d][kk] = vv[j][d];
        } else {
#pragma unroll
            for (int d = 0; d < 32; ++d) Vt[d][kk] = (f16)0;
        }
    }
    f32x4 s[4][4] = {};
#pragma unroll
    for (int mi = 0; mi < 4; ++mi)
#pragma unroll
        for (int ni = 0; ni < 4; ++ni)
            s[mi][ni] = __builtin_amdgcn_mfma_f32_16x16x32_f16(qf[mi], kf[ni], s[mi][ni], 0, 0, 0);

    __syncthreads();
#pragma unroll
    for (int mi = 0; mi < 4; ++mi) {
#pragma unroll
        for (int r = 0; r < 4; ++r) {
            float vals[4];
            float mx = -1e30f;
#pragma unroll
            for (int ni = 0; ni < 4; ++ni) {
                int col = ni * 16 + lr;
                vals[ni] = s[mi][ni][r];
                if (col < 49) mx = fmaxf(mx, vals[ni]);
            }
#pragma unroll
            for (int d = 8; d >= 1; d >>= 1) mx = fmaxf(mx, __shfl_xor(mx, d, 64));
            float p[4], sum = 0.f;
#pragma unroll
            for (int ni = 0; ni < 4; ++ni) {
                int col = ni * 16 + lr;
                p[ni] = (col < 49) ? __expf(vals[ni] - mx) : 0.f;
                sum += p[ni];
            }
#pragma unroll
            for (int d = 8; d >= 1; d >>= 1) sum += __shfl_xor(sum, d, 64);
            float is = 1.f / sum;
            int row = mi * 16 + g * 4 + r;
#pragma unroll
            for (int ni = 0; ni < 4; ++ni)
                P[row][ni * 16 + lr] = (f16)(p[ni] * is);
        }
    }
    __syncthreads();

    f32x4 o[4][2] = {};
#pragma unroll
    for (int ks = 0; ks < 2; ++ks) {
        f16x8 pa[4], vb[2];
#pragma unroll
        for (int mi = 0; mi < 4; ++mi)
            pa[mi] = *reinterpret_cast<const f16x8*>(&P[mi * 16 + lr][ks * 32 + g * 8]);
#pragma unroll
        for (int ni = 0; ni < 2; ++ni)
            vb[ni] = *reinterpret_cast<const f16x8*>(&Vt[ni * 16 + lr][ks * 32 + g * 8]);
#pragma unroll
        for (int mi = 0; mi < 4; ++mi)
#pragma unroll
            for (int ni = 0; ni < 2; ++ni)
                o[mi][ni] = __builtin_amdgcn_mfma_f32_16x16x32_f16(pa[mi], vb[ni], o[mi][ni], 0, 0, 0);
    }
#pragma unroll
    for (int mi = 0; mi < 4; ++mi)
#pragma unroll
        for (int r = 0; r < 4; ++r) {
            int row = mi * 16 + g * 4 + r;
            if (row < 49) {
                size_t off = (size_t)tok(row) * QKVN + h * 32;
#pragma unroll
                for (int ni = 0; ni < 2; ++ni)
                    QKV[off + ni * 16 + lr] = (f16)o[mi][ni][r];
            }
        }
}

// ---------------- Kernel 3: out = o @ out_w^T + out_b ----------------
// A-tile (fp16, stride 768) via global_load_lds + swizzle; B-tile fp32->fp16 cvt staging.
__global__ __launch_bounds__(256) void out_gemm(
    const f16* __restrict__ O,      // rows stride 768, first 256 halves = o
    const float* __restrict__ W,    // [256,256]
    const float* __restrict__ bias, // [256]
    float* __restrict__ OUT)        // [100352,256]
{
    __shared__ f16 As[128 * 64];
    __shared__ f16 Bs[128][LDSK];
    const int tid  = threadIdx.x;
    const int lane = tid & 63;
    const int wave = tid >> 6;
    int wg = blockIdx.x;
    const int cpx = (NTOK / 128) * (DMODEL / 128) / 8;   // 1568/8
    wg = (wg & 7) * cpx + (wg >> 3);
    const int m0 = (wg / (DMODEL / 128)) * 128;
    const int n0 = (wg % (DMODEL / 128)) * 128;
    const int wm = (wave >> 1) * 64;
    const int wn = (wave & 1) * 64;
    const int g  = lane >> 4;
    const int lr = lane & 15;

    f32x4 acc[4][4] = {};

    for (int k0 = 0; k0 < 256; k0 += 64) {
#pragma unroll
        for (int j = 0; j < 4; ++j) {
            int s   = wave * 64 + lane + j * 256;
            int row = s >> 3;
            int cs  = (s & 7) ^ (row & 7);
            gload16(O + (size_t)(m0 + row) * QKVN + k0 + cs * 8,
                    &As[(size_t)(wave * 64 + j * 256) * 8]);
        }
#pragma unroll
        for (int j = 0; j < 8; ++j) {
            int v = tid + j * 256;
            int row = v >> 4, cv = v & 15;
            float4 f = *reinterpret_cast<const float4*>(W + (size_t)(n0 + row) * 256 + k0 + cv * 4);
            f16x4 h; h[0]=(f16)f.x; h[1]=(f16)f.y; h[2]=(f16)f.z; h[3]=(f16)f.w;
            *reinterpret_cast<f16x4*>(&Bs[row][cv * 4]) = h;
        }
        __syncthreads();
#pragma unroll
        for (int ks = 0; ks < 2; ++ks) {
            f16x8 a[4], b[4];
#pragma unroll
            for (int i = 0; i < 4; ++i) {
                int row = wm + i * 16 + lr;
                int c   = ((ks << 2) + g) ^ (row & 7);
                a[i] = *reinterpret_cast<const f16x8*>(&As[row * 64 + c * 8]);
            }
#pragma unroll
            for (int i = 0; i < 4; ++i)
                b[i] = *reinterpret_cast<const f16x8*>(&Bs[wn + i * 16 + lr][ks * 32 + g * 8]);
#pragma unroll
            for (int mi = 0; mi < 4; ++mi)
#pragma unroll
                for (int ni = 0; ni < 4; ++ni)
                    acc[mi][ni] = __builtin_amdgcn_mfma_f32_16x16x32_f16(a[mi], b[ni], acc[mi][ni], 0, 0, 0);
        }
        __syncthreads();
    }
#pragma unroll
    for (int ni = 0; ni < 4; ++ni) {
        int n = n0 + wn + ni * 16 + lr;
        float bv = bias[n];
#pragma unroll
        for (int mi = 0; mi < 4; ++mi)
#pragma unroll
            for (int r = 0; r < 4; ++r) {
                int m = m0 + wm + mi * 16 + g * 4 + r;
                OUT[(size_t)m * 256 + n] = acc[mi][ni][r] + bv;
            }
    }
}

extern "C" void kernel_launch(void* const* d_in, const int* in_sizes, int n_in,
                              void* d_out, int out_size, void* d_ws, size_t ws_size,
                              hipStream_t stream) {
    const float* x     = (const float*)d_in[0];
    const float* in_w  = (const float*)d_in[1];
    const float* in_b  = (const float*)d_in[2];
    const float* out_w = (const float*)d_in[3];
    const float* out_b = (const float*)d_in[4];
    float* out = (float*)d_out;
    f16* qkv = (f16*)d_ws;               // 154,140,672 B

    // d_out as pre-GEMM scratch (overwritten by out_gemm at the end)
    f16* xh  = (f16*)d_out;              // 25,690,112 halves
    f16* wqh = xh + (size_t)NTOK * 256;  // 196,608 halves (q rows pre-scaled)

    convert_all<<<2048, 256, 0, stream>>>(x, in_w, xh, wqh);

    qkv_gemm<<<(NTOK / 128) * (QKVN / 128), 256, 0, stream>>>(xh, wqh, in_b, qkv);

    win_attn<<<2048 * 8, 64, 0, stream>>>(qkv);

    out_gemm<<<(NTOK / 128) * (DMODEL / 128), 256, 0, stream>>>(qkv, out_w, out_b, out);
}